// Round 1
// 1196.472 us; speedup vs baseline: 1.4579x; 1.4579x over previous
//
#include <hip/hip_runtime.h>
#include <math.h>

#define D_MODEL   1024
#define NUM_HEADS 16
#define DEPTH     64
#define S_LEN     2048
#define BATCH     2

typedef __attribute__((ext_vector_type(4))) float  f32x4;
typedef __attribute__((ext_vector_type(8))) __bf16 bf16x8;
typedef __attribute__((ext_vector_type(4))) __bf16 bf16x4;

// fp32 -> bf16 hi/lo split: x ~= hi + lo with ~2^-18 relative residual.
__device__ __forceinline__ void split2(float x, __bf16& h, __bf16& l) {
    h = (__bf16)x;
    l = (__bf16)(x - (float)h);
}

// 16B-slot byte offset in a fragment-ordered half-buffer for a [R rows][64 k] bf16 tile.
// Fragment (r>>4, k>>5) is 1 KiB: lane slot = (k>>3)&3 group of 16 rows; lane reads slot=lane.
__device__ __forceinline__ int frag_off(int r, int k) {
    return (((r >> 4) * 2 + (k >> 5)) << 10) + (((((k >> 3) & 3) << 4) + (r & 15)) << 4);
}

__device__ __forceinline__ f32x4 mm16(bf16x8 a, bf16x8 b, f32x4 c) {
    return __builtin_amdgcn_mfma_f32_16x16x32_bf16(a, b, c, 0, 0, 0);
}

// convert 8 fp32 -> hi/lo bf16x8 and store to fragment-ordered LDS
__device__ __forceinline__ void store_split8(char* dh, char* dl, f32x4 x0, f32x4 x1) {
    bf16x8 vh, vl;
#pragma unroll
    for (int j = 0; j < 4; ++j) {
        __bf16 h, l;
        split2(x0[j], h, l); vh[j] = h;     vl[j] = l;
        split2(x1[j], h, l); vh[j + 4] = h; vl[j + 4] = l;
    }
    *(bf16x8*)dh = vh;
    *(bf16x8*)dl = vl;
}

// ---------------------------------------------------------------------------
// Weight prep: W[k][n] fp32 -> Wt_hi/Wt_lo[n][k] bf16 (transpose + split).
// z selects which of the 4 weights. Tiny kernel (4 x 4 MB).
// ---------------------------------------------------------------------------
__global__ __launch_bounds__(256) void wsplit(const float* __restrict__ w0,
                                              const float* __restrict__ w1,
                                              const float* __restrict__ w2,
                                              const float* __restrict__ w3,
                                              __bf16* __restrict__ hiAll,
                                              __bf16* __restrict__ loAll)
{
    const int z = blockIdx.z;
    const float* W = (z == 0) ? w0 : (z == 1) ? w1 : (z == 2) ? w2 : w3;
    __bf16* Hi = hiAll + (size_t)z * 1024 * 1024;
    __bf16* Lo = loAll + (size_t)z * 1024 * 1024;

    __shared__ float T[64][65];
    const int tid = threadIdx.x;
    const int k0 = blockIdx.x * 64, n0 = blockIdx.y * 64;
    const int rr = tid / 16, cc = (tid % 16) * 4;

#pragma unroll
    for (int p = 0; p < 4; ++p) {
        int r = p * 16 + rr;
        f32x4 v = *(const f32x4*)&W[(size_t)(k0 + r) * 1024 + n0 + cc];
        T[r][cc + 0] = v[0]; T[r][cc + 1] = v[1];
        T[r][cc + 2] = v[2]; T[r][cc + 3] = v[3];
    }
    __syncthreads();
#pragma unroll
    for (int p = 0; p < 4; ++p) {
        int nr = p * 16 + rr;
        bf16x4 vh, vl;
#pragma unroll
        for (int j = 0; j < 4; ++j) {
            __bf16 h, l;
            split2(T[cc + j][nr], h, l);
            vh[j] = h; vl[j] = l;
        }
        *(bf16x4*)&Hi[(size_t)(n0 + nr) * 1024 + k0 + cc] = vh;
        *(bf16x4*)&Lo[(size_t)(n0 + nr) * 1024 + k0 + cc] = vl;
    }
}

// ---------------------------------------------------------------------------
// Split-bf16 MFMA GEMM: C = A[f32, M x 1024] * Wt^T (+bias).
// Tile 128x128, BK=64, 512 threads = 8 waves (2x4), wave tile 64x32.
// mode 0: write bf16 hi/lo head-split [bh][s][d] (Q,K)
// mode 2: write bf16 hi/lo transposed  [bh][d][s] (V)
// mode 1: write fp32 [m][n] (final out)
// ---------------------------------------------------------------------------
__global__ __launch_bounds__(512) void gemm_split(
    const float* __restrict__ A,
    const __bf16* __restrict__ BtHi, const __bf16* __restrict__ BtLo,
    const float* __restrict__ bias,
    __bf16* __restrict__ oHi, __bf16* __restrict__ oLo,
    float* __restrict__ oF, int mode)
{
    __shared__ __align__(16) char lds[65536];
    char* AH = lds;
    char* AL = lds + 16384;
    char* BH = lds + 32768;
    char* BL = lds + 49152;

    const int tid = threadIdx.x;
    const int lane = tid & 63, wid = tid >> 6;
    const int wm = wid >> 2, wn = wid & 3;
    const int bm = blockIdx.x * 128, bn = blockIdx.y * 128;

    // staging geometry: thread -> (row, 8-wide k chunk); two row-halves (r0, r0+64)
    const int r0 = tid >> 3, kc8 = (tid & 7) * 8;
    const int r1 = r0 + 64;
    const size_t a0 = (size_t)(bm + r0) * 1024 + kc8;
    const size_t a1 = (size_t)(bm + r1) * 1024 + kc8;
    const size_t b0 = (size_t)(bn + r0) * 1024 + kc8;
    const size_t b1 = (size_t)(bn + r1) * 1024 + kc8;
    const int la0 = frag_off(r0, kc8), la1 = frag_off(r1, kc8);

    const f32x4 zero = {0.f, 0.f, 0.f, 0.f};
    f32x4 acc[4][2];
#pragma unroll
    for (int i = 0; i < 4; ++i) { acc[i][0] = zero; acc[i][1] = zero; }

    // pipeline registers: preload K-step 0
    f32x4 ax00 = *(const f32x4*)(A + a0);
    f32x4 ax01 = *(const f32x4*)(A + a0 + 4);
    f32x4 ax10 = *(const f32x4*)(A + a1);
    f32x4 ax11 = *(const f32x4*)(A + a1 + 4);
    bf16x8 bh0 = *(const bf16x8*)(BtHi + b0);
    bf16x8 bh1 = *(const bf16x8*)(BtHi + b1);
    bf16x8 bl0 = *(const bf16x8*)(BtLo + b0);
    bf16x8 bl1 = *(const bf16x8*)(BtLo + b1);

    for (int k0 = 0; k0 < 1024; k0 += 64) {
        __syncthreads();                       // previous compute done, LDS writable
        store_split8(AH + la0, AL + la0, ax00, ax01);
        store_split8(AH + la1, AL + la1, ax10, ax11);
        *(bf16x8*)(BH + la0) = bh0;
        *(bf16x8*)(BH + la1) = bh1;
        *(bf16x8*)(BL + la0) = bl0;
        *(bf16x8*)(BL + la1) = bl1;
        __syncthreads();                       // tile visible
        if (k0 + 64 < 1024) {                  // issue next-tile loads early (overlap compute)
            const int kn = k0 + 64;
            ax00 = *(const f32x4*)(A + a0 + kn);
            ax01 = *(const f32x4*)(A + a0 + kn + 4);
            ax10 = *(const f32x4*)(A + a1 + kn);
            ax11 = *(const f32x4*)(A + a1 + kn + 4);
            bh0 = *(const bf16x8*)(BtHi + b0 + kn);
            bh1 = *(const bf16x8*)(BtHi + b1 + kn);
            bl0 = *(const bf16x8*)(BtLo + b0 + kn);
            bl1 = *(const bf16x8*)(BtLo + b1 + kn);
        }
#pragma unroll
        for (int kf = 0; kf < 2; ++kf) {
            bf16x8 fah[4], fal[4], fbh[2], fbl[2];
#pragma unroll
            for (int mf = 0; mf < 4; ++mf) {
                const int off = (((wm * 4 + mf) * 2 + kf) << 10) + lane * 16;
                fah[mf] = *(const bf16x8*)(AH + off);
                fal[mf] = *(const bf16x8*)(AL + off);
            }
#pragma unroll
            for (int nf = 0; nf < 2; ++nf) {
                const int off = (((wn * 2 + nf) * 2 + kf) << 10) + lane * 16;
                fbh[nf] = *(const bf16x8*)(BH + off);
                fbl[nf] = *(const bf16x8*)(BL + off);
            }
#pragma unroll
            for (int mf = 0; mf < 4; ++mf)
#pragma unroll
                for (int nf = 0; nf < 2; ++nf) {
                    acc[mf][nf] = mm16(fal[mf], fbh[nf], acc[mf][nf]);
                    acc[mf][nf] = mm16(fah[mf], fbl[nf], acc[mf][nf]);
                    acc[mf][nf] = mm16(fah[mf], fbh[nf], acc[mf][nf]);
                }
        }
    }

    // epilogue: C/D layout col=lane&15, row=(lane>>4)*4+reg  [m89-verified]
    const int rbase = (lane >> 4) * 4;
    const int cloc = lane & 15;
#pragma unroll
    for (int mf = 0; mf < 4; ++mf) {
        const int m0g = bm + wm * 64 + mf * 16 + rbase;
#pragma unroll
        for (int nf = 0; nf < 2; ++nf) {
            const int n_g = bn + wn * 32 + nf * 16 + cloc;
            const float bv = bias[n_g];
            float v[4];
#pragma unroll
            for (int r = 0; r < 4; ++r) v[r] = acc[mf][nf][r] + bv;
            if (mode == 1) {
#pragma unroll
                for (int r = 0; r < 4; ++r) oF[(size_t)(m0g + r) * 1024 + n_g] = v[r];
            } else {
                const int bb = m0g >> 11;
                const int sloc = m0g & 2047;
                const int h = n_g >> 6, d = n_g & 63;
                if (mode == 0) {
                    const size_t i0 = ((size_t)(bb * 16 + h) * 2048 + sloc) * 64 + d;
#pragma unroll
                    for (int r = 0; r < 4; ++r) {
                        __bf16 hh, ll;
                        split2(v[r], hh, ll);
                        oHi[i0 + (size_t)r * 64] = hh;
                        oLo[i0 + (size_t)r * 64] = ll;
                    }
                } else {  // mode 2: Vt[bh][d][s], pack 4 consecutive s
                    const size_t i0 = ((size_t)(bb * 16 + h) * 64 + d) * 2048 + sloc;
                    bf16x4 vh, vl;
#pragma unroll
                    for (int r = 0; r < 4; ++r) {
                        __bf16 hh, ll;
                        split2(v[r], hh, ll);
                        vh[r] = hh; vl[r] = ll;
                    }
                    *(bf16x4*)&oHi[i0] = vh;
                    *(bf16x4*)&oLo[i0] = vl;
                }
            }
        }
    }
}

// ---------------------------------------------------------------------------
// scores: logits = scale * Q K^T per (b,h). Q/K pre-split bf16 [bh][s][64].
// 128x128 tile, single K-step (K=64), 512 threads.
// ---------------------------------------------------------------------------
__global__ __launch_bounds__(512) void scores_mfma(
    const __bf16* __restrict__ QHi, const __bf16* __restrict__ QLo,
    const __bf16* __restrict__ KHi, const __bf16* __restrict__ KLo,
    float* __restrict__ attn)
{
    __shared__ __align__(16) char lds[65536];
    char* QH = lds;
    char* QL = lds + 16384;
    char* KH = lds + 32768;
    char* KL = lds + 49152;

    const int tid = threadIdx.x;
    const int lane = tid & 63, wid = tid >> 6;
    const int wm = wid >> 2, wn = wid & 3;
    const int m0 = blockIdx.x * 128, n0 = blockIdx.y * 128;
    const int bh = blockIdx.z;

    const __bf16* Qh_ = QHi + (size_t)bh * S_LEN * 64;
    const __bf16* Ql_ = QLo + (size_t)bh * S_LEN * 64;
    const __bf16* Kh_ = KHi + (size_t)bh * S_LEN * 64;
    const __bf16* Kl_ = KLo + (size_t)bh * S_LEN * 64;

    const int r0 = tid >> 3, kc8 = (tid & 7) * 8;
    const int r1 = r0 + 64;
    const int l0 = frag_off(r0, kc8), l1 = frag_off(r1, kc8);
    const size_t q0 = (size_t)(m0 + r0) * 64 + kc8;
    const size_t q1 = (size_t)(m0 + r1) * 64 + kc8;
    const size_t k0 = (size_t)(n0 + r0) * 64 + kc8;
    const size_t k1 = (size_t)(n0 + r1) * 64 + kc8;

    *(bf16x8*)(QH + l0) = *(const bf16x8*)(Qh_ + q0);
    *(bf16x8*)(QH + l1) = *(const bf16x8*)(Qh_ + q1);
    *(bf16x8*)(QL + l0) = *(const bf16x8*)(Ql_ + q0);
    *(bf16x8*)(QL + l1) = *(const bf16x8*)(Ql_ + q1);
    *(bf16x8*)(KH + l0) = *(const bf16x8*)(Kh_ + k0);
    *(bf16x8*)(KH + l1) = *(const bf16x8*)(Kh_ + k1);
    *(bf16x8*)(KL + l0) = *(const bf16x8*)(Kl_ + k0);
    *(bf16x8*)(KL + l1) = *(const bf16x8*)(Kl_ + k1);
    __syncthreads();

    const f32x4 zero = {0.f, 0.f, 0.f, 0.f};
    f32x4 acc[4][2];
#pragma unroll
    for (int i = 0; i < 4; ++i) { acc[i][0] = zero; acc[i][1] = zero; }

#pragma unroll
    for (int kf = 0; kf < 2; ++kf) {
        bf16x8 fah[4], fal[4], fbh[2], fbl[2];
#pragma unroll
        for (int mf = 0; mf < 4; ++mf) {
            const int off = (((wm * 4 + mf) * 2 + kf) << 10) + lane * 16;
            fah[mf] = *(const bf16x8*)(QH + off);
            fal[mf] = *(const bf16x8*)(QL + off);
        }
#pragma unroll
        for (int nf = 0; nf < 2; ++nf) {
            const int off = (((wn * 2 + nf) * 2 + kf) << 10) + lane * 16;
            fbh[nf] = *(const bf16x8*)(KH + off);
            fbl[nf] = *(const bf16x8*)(KL + off);
        }
#pragma unroll
        for (int mf = 0; mf < 4; ++mf)
#pragma unroll
            for (int nf = 0; nf < 2; ++nf) {
                acc[mf][nf] = mm16(fal[mf], fbh[nf], acc[mf][nf]);
                acc[mf][nf] = mm16(fah[mf], fbl[nf], acc[mf][nf]);
                acc[mf][nf] = mm16(fah[mf], fbh[nf], acc[mf][nf]);
            }
    }

    float* C = attn + (size_t)bh * S_LEN * S_LEN;
    const int rbase = (lane >> 4) * 4, cloc = lane & 15;
#pragma unroll
    for (int mf = 0; mf < 4; ++mf) {
        const int m0g = m0 + wm * 64 + mf * 16 + rbase;
#pragma unroll
        for (int nf = 0; nf < 2; ++nf) {
            const int n_g = n0 + wn * 32 + nf * 16 + cloc;
#pragma unroll
            for (int r = 0; r < 4; ++r)
                C[(size_t)(m0g + r) * S_LEN + n_g] = acc[mf][nf][r] * 0.125f;
        }
    }
}

// ---------------------------------------------------------------------------
// softmax: rowwise in place; one 256-thread block per row (unchanged, ~BW-bound)
// ---------------------------------------------------------------------------
__global__ __launch_bounds__(256) void softmax_kernel(float* __restrict__ attn)
{
    const size_t row = blockIdx.x;
    float* p = attn + row * (size_t)S_LEN;
    const int tid = threadIdx.x;

    float4 v0 = ((const float4*)p)[tid];
    float4 v1 = ((const float4*)p)[tid + 256];

    float m = fmaxf(fmaxf(fmaxf(v0.x, v0.y), fmaxf(v0.z, v0.w)),
                    fmaxf(fmaxf(v1.x, v1.y), fmaxf(v1.z, v1.w)));
#pragma unroll
    for (int off = 32; off > 0; off >>= 1) m = fmaxf(m, __shfl_xor(m, off));

    __shared__ float redm[4];
    __shared__ float reds[4];
    const int wave = tid >> 6, lane = tid & 63;
    if (lane == 0) redm[wave] = m;
    __syncthreads();
    m = fmaxf(fmaxf(redm[0], redm[1]), fmaxf(redm[2], redm[3]));

    v0.x = __expf(v0.x - m); v0.y = __expf(v0.y - m);
    v0.z = __expf(v0.z - m); v0.w = __expf(v0.w - m);
    v1.x = __expf(v1.x - m); v1.y = __expf(v1.y - m);
    v1.z = __expf(v1.z - m); v1.w = __expf(v1.w - m);

    float s = v0.x + v0.y + v0.z + v0.w + v1.x + v1.y + v1.z + v1.w;
#pragma unroll
    for (int off = 32; off > 0; off >>= 1) s += __shfl_xor(s, off);
    if (lane == 0) reds[wave] = s;
    __syncthreads();
    s = reds[0] + reds[1] + reds[2] + reds[3];

    const float inv = 1.0f / s;
    v0.x *= inv; v0.y *= inv; v0.z *= inv; v0.w *= inv;
    v1.x *= inv; v1.y *= inv; v1.z *= inv; v1.w *= inv;
    ((float4*)p)[tid]       = v0;
    ((float4*)p)[tid + 256] = v1;
}

// ---------------------------------------------------------------------------
// ctx = attn[bh] (2048x2048, f32, split in staging) @ V^T-stored (Vt[bh][d][s] bf16 hi/lo)
// Tile 128(m) x 64(n), BK=64, 256 threads = 4 waves (2x2), wave tile 64x32.
// ---------------------------------------------------------------------------
__global__ __launch_bounds__(256) void ctx_mfma(
    const float* __restrict__ attn,
    const __bf16* __restrict__ VtHi, const __bf16* __restrict__ VtLo,
    float* __restrict__ ctx)
{
    __shared__ __align__(16) char lds[49152];
    char* AH = lds;
    char* AL = lds + 16384;
    char* BH = lds + 32768;
    char* BL = lds + 40960;

    const int tid = threadIdx.x;
    const int lane = tid & 63, wid = tid >> 6;
    const int wm = wid >> 1, wn = wid & 1;
    const int bm = blockIdx.x * 128;
    const int bh = blockIdx.y;
    const int bb = bh >> 4, h = bh & 15;

    const float* Ab = attn + (size_t)bh * S_LEN * S_LEN + (size_t)bm * S_LEN;
    const __bf16* Vh_ = VtHi + (size_t)bh * 64 * S_LEN;
    const __bf16* Vl_ = VtLo + (size_t)bh * 64 * S_LEN;

    const int r0 = tid >> 3, kc8 = (tid & 7) * 8;  // 32 rows per pass
    size_t aoff[4]; int la[4];
#pragma unroll
    for (int p = 0; p < 4; ++p) {
        aoff[p] = (size_t)(r0 + p * 32) * S_LEN + kc8;
        la[p] = frag_off(r0 + p * 32, kc8);
    }
    size_t boff[2]; int lb[2];
#pragma unroll
    for (int p = 0; p < 2; ++p) {
        boff[p] = (size_t)(r0 + p * 32) * S_LEN + kc8;
        lb[p] = frag_off(r0 + p * 32, kc8);
    }

    const f32x4 zero = {0.f, 0.f, 0.f, 0.f};
    f32x4 acc[4][2];
#pragma unroll
    for (int i = 0; i < 4; ++i) { acc[i][0] = zero; acc[i][1] = zero; }

    f32x4 ax[4][2];
    bf16x8 bxh[2], bxl[2];
#pragma unroll
    for (int p = 0; p < 4; ++p) {
        ax[p][0] = *(const f32x4*)(Ab + aoff[p]);
        ax[p][1] = *(const f32x4*)(Ab + aoff[p] + 4);
    }
#pragma unroll
    for (int p = 0; p < 2; ++p) {
        bxh[p] = *(const bf16x8*)(Vh_ + boff[p]);
        bxl[p] = *(const bf16x8*)(Vl_ + boff[p]);
    }

    for (int s0 = 0; s0 < S_LEN; s0 += 64) {
        __syncthreads();
#pragma unroll
        for (int p = 0; p < 4; ++p) store_split8(AH + la[p], AL + la[p], ax[p][0], ax[p][1]);
#pragma unroll
        for (int p = 0; p < 2; ++p) {
            *(bf16x8*)(BH + lb[p]) = bxh[p];
            *(bf16x8*)(BL + lb[p]) = bxl[p];
        }
        __syncthreads();
        if (s0 + 64 < S_LEN) {
            const int sn = s0 + 64;
#pragma unroll
            for (int p = 0; p < 4; ++p) {
                ax[p][0] = *(const f32x4*)(Ab + aoff[p] + sn);
                ax[p][1] = *(const f32x4*)(Ab + aoff[p] + sn + 4);
            }
#pragma unroll
            for (int p = 0; p < 2; ++p) {
                bxh[p] = *(const bf16x8*)(Vh_ + boff[p] + sn);
                bxl[p] = *(const bf16x8*)(Vl_ + boff[p] + sn);
            }
        }
#pragma unroll
        for (int kf = 0; kf < 2; ++kf) {
            bf16x8 fah[4], fal[4], fbh[2], fbl[2];
#pragma unroll
            for (int mf = 0; mf < 4; ++mf) {
                const int off = (((wm * 4 + mf) * 2 + kf) << 10) + lane * 16;
                fah[mf] = *(const bf16x8*)(AH + off);
                fal[mf] = *(const bf16x8*)(AL + off);
            }
#pragma unroll
            for (int nf = 0; nf < 2; ++nf) {
                const int off = (((wn * 2 + nf) * 2 + kf) << 10) + lane * 16;
                fbh[nf] = *(const bf16x8*)(BH + off);
                fbl[nf] = *(const bf16x8*)(BL + off);
            }
#pragma unroll
            for (int mf = 0; mf < 4; ++mf)
#pragma unroll
                for (int nf = 0; nf < 2; ++nf) {
                    acc[mf][nf] = mm16(fal[mf], fbh[nf], acc[mf][nf]);
                    acc[mf][nf] = mm16(fah[mf], fbl[nf], acc[mf][nf]);
                    acc[mf][nf] = mm16(fah[mf], fbh[nf], acc[mf][nf]);
                }
        }
    }

    const int rbase = (lane >> 4) * 4, cloc = lane & 15;
#pragma unroll
    for (int mf = 0; mf < 4; ++mf) {
        const int sg0 = bm + wm * 64 + mf * 16 + rbase;
#pragma unroll
        for (int nf = 0; nf < 2; ++nf) {
            const int d = wn * 32 + nf * 16 + cloc;
#pragma unroll
            for (int r = 0; r < 4; ++r)
                ctx[((size_t)bb * S_LEN + sg0 + r) * D_MODEL + h * 64 + d] = acc[mf][nf][r];
        }
    }
}

// ---------------------------------------------------------------------------
extern "C" void kernel_launch(void* const* d_in, const int* in_sizes, int n_in,
                              void* d_out, int out_size, void* d_ws, size_t ws_size,
                              hipStream_t stream)
{
    const float* q  = (const float*)d_in[0];
    const float* k  = (const float*)d_in[1];
    const float* v  = (const float*)d_in[2];
    const float* wq = (const float*)d_in[3];
    const float* bq = (const float*)d_in[4];
    const float* wk = (const float*)d_in[5];
    const float* bk = (const float*)d_in[6];
    const float* wv = (const float*)d_in[7];
    const float* bv = (const float*)d_in[8];
    const float* wo = (const float*)d_in[9];
    const float* bo = (const float*)d_in[10];

    float* out  = (float*)d_out;                          // [2,2048,1024]
    float* attn = out + (size_t)BATCH * S_LEN * D_MODEL;  // [2,16,2048,2048]

    // workspace layout (64 MB total):
    //   [0,8)MB Wt_hi[4], [8,16) Wt_lo[4], [16,24) Q_hi, [24,32) Q_lo,
    //   [32,40) K_hi, [40,48) K_lo, [48,56) Vt_hi, [56,64) Vt_lo
    //   ctx fp32 (16 MB) aliases Q_hi/Q_lo (dead after scores).
    char* ws = (char*)d_ws;
    const size_t MB = 1024 * 1024;
    __bf16* WT_HI = (__bf16*)(ws);
    __bf16* WT_LO = (__bf16*)(ws + 8 * MB);
    __bf16* QHI   = (__bf16*)(ws + 16 * MB);
    __bf16* QLO   = (__bf16*)(ws + 24 * MB);
    __bf16* KHI   = (__bf16*)(ws + 32 * MB);
    __bf16* KLO   = (__bf16*)(ws + 40 * MB);
    __bf16* VTHI  = (__bf16*)(ws + 48 * MB);
    __bf16* VTLO  = (__bf16*)(ws + 56 * MB);
    float*  ctxb  = (float*)(ws + 16 * MB);
    const size_t WSTRIDE = 1024 * 1024;  // elements per weight

    // weight transpose+split (z: 0=wq 1=wk 2=wv 3=wo)
    wsplit<<<dim3(16, 16, 4), dim3(256), 0, stream>>>(wq, wk, wv, wo, WT_HI, WT_LO);

    // projections (MFMA split-bf16)
    gemm_split<<<dim3(32, 8), dim3(512), 0, stream>>>(q, WT_HI + 0 * WSTRIDE, WT_LO + 0 * WSTRIDE,
                                                      bq, QHI, QLO, nullptr, 0);
    gemm_split<<<dim3(32, 8), dim3(512), 0, stream>>>(k, WT_HI + 1 * WSTRIDE, WT_LO + 1 * WSTRIDE,
                                                      bk, KHI, KLO, nullptr, 0);
    gemm_split<<<dim3(32, 8), dim3(512), 0, stream>>>(v, WT_HI + 2 * WSTRIDE, WT_LO + 2 * WSTRIDE,
                                                      bv, VTHI, VTLO, nullptr, 2);

    // logits -> attn (raw scaled), softmax in place
    scores_mfma<<<dim3(16, 16, BATCH * NUM_HEADS), dim3(512), 0, stream>>>(QHI, QLO, KHI, KLO, attn);
    softmax_kernel<<<dim3(BATCH * NUM_HEADS * S_LEN), dim3(256), 0, stream>>>(attn);

    // ctx = attn @ V  (scatter to [B,S,D_MODEL])
    ctx_mfma<<<dim3(16, BATCH * NUM_HEADS), dim3(256), 0, stream>>>(attn, VTHI, VTLO, ctxb);

    // output projection
    gemm_split<<<dim3(32, 8), dim3(512), 0, stream>>>(ctxb, WT_HI + 3 * WSTRIDE, WT_LO + 3 * WSTRIDE,
                                                      bo, nullptr, nullptr, out, 1);
}

// Round 3
// 1086.034 us; speedup vs baseline: 1.6061x; 1.1017x over previous
//
#include <hip/hip_runtime.h>
#include <math.h>

#define D_MODEL   1024
#define NUM_HEADS 16
#define DEPTH     64
#define S_LEN     2048
#define BATCH     2

typedef __attribute__((ext_vector_type(4))) float  f32x4;
typedef __attribute__((ext_vector_type(8))) __bf16 bf16x8;
typedef __attribute__((ext_vector_type(4))) __bf16 bf16x4;

// fp32 -> bf16 hi/lo split: x ~= hi + lo with ~2^-18 relative residual.
__device__ __forceinline__ void split2(float x, __bf16& h, __bf16& l) {
    h = (__bf16)x;
    l = (__bf16)(x - (float)h);
}

// fragment-ordered LDS byte offset; tile = [rows][kwidth] bf16.
// fragment (r>>4, k>>5) is 1 KiB; lane slot = ((k>>3)&3)*16 + (r&15); 16B/slot.
__device__ __forceinline__ int frag2(int r, int k) {   // kwidth 64
    return (((r >> 4) * 2 + (k >> 5)) << 10) + (((k >> 3) & 3) << 8) + ((r & 15) << 4);
}
__device__ __forceinline__ int frag4(int r, int k) {   // kwidth 128
    return (((r >> 4) * 4 + (k >> 5)) << 10) + (((k >> 3) & 3) << 8) + ((r & 15) << 4);
}

__device__ __forceinline__ f32x4 mm16(bf16x8 a, bf16x8 b, f32x4 c) {
    return __builtin_amdgcn_mfma_f32_16x16x32_bf16(a, b, c, 0, 0, 0);
}

__device__ __forceinline__ void split8(f32x4 x0, f32x4 x1, bf16x8& vh, bf16x8& vl) {
#pragma unroll
    for (int j = 0; j < 4; ++j) {
        __bf16 h, l;
        split2(x0[j], h, l); vh[j] = h;     vl[j] = l;
        split2(x1[j], h, l); vh[j + 4] = h; vl[j + 4] = l;
    }
}

// ---------------------------------------------------------------------------
// Weight prep: W[k][n] fp32 -> Wt_hi/Wt_lo[n][k] bf16 (transpose + split).
// z: 0=wq 1=wk 2=wv 3=wo.  Layout (bytes in ws): wo hi@0 lo@2MB; wq hi@4 lo@6;
// wk hi@8 lo@10; wv hi@12 lo@14.
// ---------------------------------------------------------------------------
__global__ __launch_bounds__(256) void wsplit(const float* __restrict__ w0,
                                              const float* __restrict__ w1,
                                              const float* __restrict__ w2,
                                              const float* __restrict__ w3,
                                              __bf16* __restrict__ base)
{
    const int z = blockIdx.z;
    const float* W = (z == 0) ? w0 : (z == 1) ? w1 : (z == 2) ? w2 : w3;
    const size_t hi_off = (z == 3) ? 0 : (size_t)(z + 1) * 2097152;
    __bf16* Hi = base + hi_off;
    __bf16* Lo = Hi + 1048576;

    __shared__ float T[64][65];
    const int tid = threadIdx.x;
    const int k0 = blockIdx.x * 64, n0 = blockIdx.y * 64;
    const int rr = tid / 16, cc = (tid % 16) * 4;

#pragma unroll
    for (int p = 0; p < 4; ++p) {
        int r = p * 16 + rr;
        f32x4 v = *(const f32x4*)&W[(size_t)(k0 + r) * 1024 + n0 + cc];
        T[r][cc + 0] = v[0]; T[r][cc + 1] = v[1];
        T[r][cc + 2] = v[2]; T[r][cc + 3] = v[3];
    }
    __syncthreads();
#pragma unroll
    for (int p = 0; p < 4; ++p) {
        int nr = p * 16 + rr;
        bf16x4 vh, vl;
#pragma unroll
        for (int j = 0; j < 4; ++j) {
            __bf16 h, l;
            split2(T[cc + j][nr], h, l);
            vh[j] = h; vl[j] = l;
        }
        *(bf16x4*)&Hi[(size_t)(n0 + nr) * 1024 + k0 + cc] = vh;
        *(bf16x4*)&Lo[(size_t)(n0 + nr) * 1024 + k0 + cc] = vl;
    }
}

// ---------------------------------------------------------------------------
// Split-bf16 MFMA GEMM: C = A[f32, M x 1024] * Wt^T (+bias).
// Tile 128x128, BK=64, 512 threads = 8 waves (2x4), wave tile 64x32.
// mode 0: bf16 hi/lo head-split [bh][s][d]   (K)
// mode 3: like 0 but value *= 0.125 first    (Q, folds attn scale)
// mode 2: bf16 hi/lo transposed [bh][d][s]   (V)
// mode 1: fp32 [m][1024]                     (final out / per-batch)
// ---------------------------------------------------------------------------
__global__ __launch_bounds__(512) void gemm_split(
    const float* __restrict__ A,
    const __bf16* __restrict__ BtHi, const __bf16* __restrict__ BtLo,
    const float* __restrict__ bias,
    __bf16* __restrict__ oHi, __bf16* __restrict__ oLo,
    float* __restrict__ oF, int mode)
{
    __shared__ __align__(16) char lds[65536];
    char* AH = lds;
    char* AL = lds + 16384;
    char* BH = lds + 32768;
    char* BL = lds + 49152;

    const int tid = threadIdx.x;
    const int lane = tid & 63, wid = tid >> 6;
    const int wm = wid >> 2, wn = wid & 3;
    const int bm = blockIdx.x * 128, bn = blockIdx.y * 128;

    const int r0 = tid >> 3, kc8 = (tid & 7) * 8;
    const int r1 = r0 + 64;
    const size_t a0 = (size_t)(bm + r0) * 1024 + kc8;
    const size_t a1 = (size_t)(bm + r1) * 1024 + kc8;
    const size_t b0 = (size_t)(bn + r0) * 1024 + kc8;
    const size_t b1 = (size_t)(bn + r1) * 1024 + kc8;
    const int la0 = frag2(r0, kc8), la1 = frag2(r1, kc8);

    const f32x4 zero = {0.f, 0.f, 0.f, 0.f};
    f32x4 acc[4][2];
#pragma unroll
    for (int i = 0; i < 4; ++i) { acc[i][0] = zero; acc[i][1] = zero; }

    // prefetch K-step 0
    f32x4 x0 = *(const f32x4*)(A + a0), x1 = *(const f32x4*)(A + a0 + 4);
    f32x4 x2 = *(const f32x4*)(A + a1), x3 = *(const f32x4*)(A + a1 + 4);
    bf16x8 bh0 = *(const bf16x8*)(BtHi + b0);
    bf16x8 bh1 = *(const bf16x8*)(BtHi + b1);
    bf16x8 bl0 = *(const bf16x8*)(BtLo + b0);
    bf16x8 bl1 = *(const bf16x8*)(BtLo + b1);

    for (int k0 = 0; k0 < 1024; k0 += 64) {
        bf16x8 ah0, al0, ah1, al1;
        split8(x0, x1, ah0, al0);
        split8(x2, x3, ah1, al1);
        __syncthreads();
        *(bf16x8*)(AH + la0) = ah0; *(bf16x8*)(AL + la0) = al0;
        *(bf16x8*)(AH + la1) = ah1; *(bf16x8*)(AL + la1) = al1;
        *(bf16x8*)(BH + la0) = bh0; *(bf16x8*)(BH + la1) = bh1;
        *(bf16x8*)(BL + la0) = bl0; *(bf16x8*)(BL + la1) = bl1;
        __syncthreads();
        if (k0 + 64 < 1024) {
            const int kn = k0 + 64;
            x0 = *(const f32x4*)(A + a0 + kn); x1 = *(const f32x4*)(A + a0 + kn + 4);
            x2 = *(const f32x4*)(A + a1 + kn); x3 = *(const f32x4*)(A + a1 + kn + 4);
            bh0 = *(const bf16x8*)(BtHi + b0 + kn);
            bh1 = *(const bf16x8*)(BtHi + b1 + kn);
            bl0 = *(const bf16x8*)(BtLo + b0 + kn);
            bl1 = *(const bf16x8*)(BtLo + b1 + kn);
        }
#pragma unroll
        for (int kf = 0; kf < 2; ++kf) {
            bf16x8 fah[4], fal[4], fbh[2], fbl[2];
#pragma unroll
            for (int mf = 0; mf < 4; ++mf) {
                const int off = (((wm * 4 + mf) * 2 + kf) << 10) + lane * 16;
                fah[mf] = *(const bf16x8*)(AH + off);
                fal[mf] = *(const bf16x8*)(AL + off);
            }
#pragma unroll
            for (int nf = 0; nf < 2; ++nf) {
                const int off = (((wn * 2 + nf) * 2 + kf) << 10) + lane * 16;
                fbh[nf] = *(const bf16x8*)(BH + off);
                fbl[nf] = *(const bf16x8*)(BL + off);
            }
#pragma unroll
            for (int mf = 0; mf < 4; ++mf)
#pragma unroll
                for (int nf = 0; nf < 2; ++nf) {
                    acc[mf][nf] = mm16(fal[mf], fbh[nf], acc[mf][nf]);
                    acc[mf][nf] = mm16(fah[mf], fbl[nf], acc[mf][nf]);
                    acc[mf][nf] = mm16(fah[mf], fbh[nf], acc[mf][nf]);
                }
        }
    }

    const int rbase = (lane >> 4) * 4;
    const int cloc = lane & 15;
#pragma unroll
    for (int mf = 0; mf < 4; ++mf) {
        const int m0g = bm + wm * 64 + mf * 16 + rbase;
#pragma unroll
        for (int nf = 0; nf < 2; ++nf) {
            const int n_g = bn + wn * 32 + nf * 16 + cloc;
            const float bv = bias[n_g];
            float v[4];
#pragma unroll
            for (int r = 0; r < 4; ++r) {
                v[r] = acc[mf][nf][r] + bv;
                if (mode == 3) v[r] *= 0.125f;
            }
            if (mode == 1) {
#pragma unroll
                for (int r = 0; r < 4; ++r) oF[(size_t)(m0g + r) * 1024 + n_g] = v[r];
            } else {
                const int bb = m0g >> 11;
                const int sloc = m0g & 2047;
                const int h = n_g >> 6, d = n_g & 63;
                if (mode != 2) {   // 0 or 3: head-split [bh][s][d]
                    const size_t i0 = ((size_t)(bb * 16 + h) * 2048 + sloc) * 64 + d;
#pragma unroll
                    for (int r = 0; r < 4; ++r) {
                        __bf16 hh, ll;
                        split2(v[r], hh, ll);
                        oHi[i0 + (size_t)r * 64] = hh;
                        oLo[i0 + (size_t)r * 64] = ll;
                    }
                } else {           // 2: Vt[bh][d][s]
                    const size_t i0 = ((size_t)(bb * 16 + h) * 64 + d) * 2048 + sloc;
                    bf16x4 vh, vl;
#pragma unroll
                    for (int r = 0; r < 4; ++r) {
                        __bf16 hh, ll;
                        split2(v[r], hh, ll);
                        vh[r] = hh; vl[r] = ll;
                    }
                    *(bf16x4*)&oHi[i0] = vh;
                    *(bf16x4*)&oLo[i0] = vl;
                }
            }
        }
    }
}

// ---------------------------------------------------------------------------
// Fused flash attention for ONE batch (16 heads). Block = 128 Q-rows of one head.
// 512 threads = 8 waves (2 wm x 4 wn). Q (pre-scaled by 1/8) in registers.
// Pass A: QK^T -> online (m,l).  Pass B: recompute QK^T, write normalized attn,
// stage P hi/lo in LDS, accumulate PV -> ctx. attn written exactly once, never read.
// LDS 64KB: KV buf 32KB (K tile or V^T tile, hi+lo), PB 32KB (P half / ml scratch).
// ---------------------------------------------------------------------------
__global__ __launch_bounds__(512) void attn_fused(
    const __bf16* __restrict__ QHi, const __bf16* __restrict__ QLo,
    const __bf16* __restrict__ KHi, const __bf16* __restrict__ KLo,
    const __bf16* __restrict__ VtHi, const __bf16* __restrict__ VtLo,
    float* __restrict__ attn, float* __restrict__ ctxb)
{
    __shared__ __align__(16) char lds[65536];
    char* KV = lds;            // hi @0, lo @16384
    char* PB = lds + 32768;    // hi @0, lo @16384 ; pass A: (m,l) scratch
    float* scr = (float*)PB;   // [4 wn][128 rows][2]

    const int tid = threadIdx.x;
    const int lane = tid & 63, wid = tid >> 6;
    const int wm = wid >> 2, wn = wid & 3;

    // XCD-aware swizzle: same-head blocks co-resident on one XCD (K/V L2 reuse)
    const int id = blockIdx.x;
    const int bh = (id & 7) + (id >> 7) * 8;      // head 0..15
    const int bm = ((id >> 3) & 15) * 128;        // q-tile

    const __bf16* Qh_ = QHi + (size_t)bh * S_LEN * 64;
    const __bf16* Ql_ = QLo + (size_t)bh * S_LEN * 64;
    const __bf16* Kh_ = KHi + (size_t)bh * S_LEN * 64;
    const __bf16* Kl_ = KLo + (size_t)bh * S_LEN * 64;
    const __bf16* Vh_ = VtHi + (size_t)bh * 64 * S_LEN;
    const __bf16* Vl_ = VtLo + (size_t)bh * 64 * S_LEN;
    float* attn_b = attn + (size_t)bh * S_LEN * S_LEN;

    // Q fragments in registers (16 x bf16x8 hi + lo)
    bf16x8 qh[4][2], ql[4][2];
#pragma unroll
    for (int mf = 0; mf < 4; ++mf)
#pragma unroll
        for (int kf = 0; kf < 2; ++kf) {
            const int row = bm + wm * 64 + mf * 16 + (lane & 15);
            const int k = kf * 32 + (lane >> 4) * 8;
            qh[mf][kf] = *(const bf16x8*)(Qh_ + (size_t)row * 64 + k);
            ql[mf][kf] = *(const bf16x8*)(Ql_ + (size_t)row * 64 + k);
        }

    // staging geometry
    const int r0 = tid >> 3, kc8 = (tid & 7) * 8;
    const int lk0 = frag2(r0, kc8), lk1 = frag2(r0 + 64, kc8);
    const int lv0 = frag4(r0, kc8), lv1 = frag4(r0, kc8 + 64);

    // QK^T for tile staged in KV -> acc (zero-inited). Identical in both passes.
    auto qk_tile = [&](f32x4 (&acc)[4][2]) {
        const f32x4 z4 = {0.f, 0.f, 0.f, 0.f};
#pragma unroll
        for (int i = 0; i < 4; ++i) { acc[i][0] = z4; acc[i][1] = z4; }
#pragma unroll
        for (int kf = 0; kf < 2; ++kf) {
            bf16x8 kbh[2], kbl[2];
#pragma unroll
            for (int nf = 0; nf < 2; ++nf) {
                const int off = (((wn * 2 + nf) * 2 + kf) << 10) + lane * 16;
                kbh[nf] = *(const bf16x8*)(KV + off);
                kbl[nf] = *(const bf16x8*)(KV + 16384 + off);
            }
#pragma unroll
            for (int mf = 0; mf < 4; ++mf)
#pragma unroll
                for (int nf = 0; nf < 2; ++nf) {
                    acc[mf][nf] = mm16(ql[mf][kf], kbh[nf], acc[mf][nf]);
                    acc[mf][nf] = mm16(qh[mf][kf], kbl[nf], acc[mf][nf]);
                    acc[mf][nf] = mm16(qh[mf][kf], kbh[nf], acc[mf][nf]);
                }
        }
    };

    float m_r[4][4], l_r[4][4];
#pragma unroll
    for (int mf = 0; mf < 4; ++mf)
#pragma unroll
        for (int r = 0; r < 4; ++r) { m_r[mf][r] = -INFINITY; l_r[mf][r] = 0.f; }

    // -------- pass A: online (m,l) --------
    bf16x8 pkh0 = *(const bf16x8*)(Kh_ + (size_t)r0 * 64 + kc8);
    bf16x8 pkh1 = *(const bf16x8*)(Kh_ + (size_t)(r0 + 64) * 64 + kc8);
    bf16x8 pkl0 = *(const bf16x8*)(Kl_ + (size_t)r0 * 64 + kc8);
    bf16x8 pkl1 = *(const bf16x8*)(Kl_ + (size_t)(r0 + 64) * 64 + kc8);

    for (int t = 0; t < 16; ++t) {
        __syncthreads();
        *(bf16x8*)(KV + lk0) = pkh0; *(bf16x8*)(KV + lk1) = pkh1;
        *(bf16x8*)(KV + 16384 + lk0) = pkl0; *(bf16x8*)(KV + 16384 + lk1) = pkl1;
        __syncthreads();
        if (t < 15) {
            const size_t g = (size_t)((t + 1) * 128) * 64 + kc8;
            pkh0 = *(const bf16x8*)(Kh_ + g + (size_t)r0 * 64);
            pkh1 = *(const bf16x8*)(Kh_ + g + (size_t)(r0 + 64) * 64);
            pkl0 = *(const bf16x8*)(Kl_ + g + (size_t)r0 * 64);
            pkl1 = *(const bf16x8*)(Kl_ + g + (size_t)(r0 + 64) * 64);
        }
        f32x4 acc[4][2];
        qk_tile(acc);
#pragma unroll
        for (int mf = 0; mf < 4; ++mf)
#pragma unroll
            for (int r = 0; r < 4; ++r) {
                const float s0 = acc[mf][0][r], s1 = acc[mf][1][r];
                const float mo = m_r[mf][r];
                const float mn = fmaxf(mo, fmaxf(s0, s1));
                l_r[mf][r] = l_r[mf][r] * __expf(mo - mn) + __expf(s0 - mn) + __expf(s1 - mn);
                m_r[mf][r] = mn;
            }
    }

    // reduce over the 16-lane col groups (butterfly; all lanes get result)
#pragma unroll
    for (int mf = 0; mf < 4; ++mf)
#pragma unroll
        for (int r = 0; r < 4; ++r) {
            float m = m_r[mf][r], l = l_r[mf][r];
#pragma unroll
            for (int mask = 1; mask < 16; mask <<= 1) {
                const float m2 = __shfl_xor(m, mask);
                const float l2 = __shfl_xor(l, mask);
                const float mm = fmaxf(m, m2);
                l = l * __expf(m - mm) + l2 * __expf(m2 - mm);
                m = mm;
            }
            m_r[mf][r] = m; l_r[mf][r] = l;
        }
    // cross-wave (4 wn waves share rows) via LDS scratch
    if ((lane & 15) == 0) {
#pragma unroll
        for (int mf = 0; mf < 4; ++mf)
#pragma unroll
            for (int r = 0; r < 4; ++r) {
                const int row = wm * 64 + mf * 16 + (lane >> 4) * 4 + r;
                scr[(wn * 128 + row) * 2 + 0] = m_r[mf][r];
                scr[(wn * 128 + row) * 2 + 1] = l_r[mf][r];
            }
    }
    __syncthreads();
#pragma unroll
    for (int mf = 0; mf < 4; ++mf)
#pragma unroll
        for (int r = 0; r < 4; ++r) {
            const int row = wm * 64 + mf * 16 + (lane >> 4) * 4 + r;
            float m = scr[row * 2 + 0], l = scr[row * 2 + 1];
#pragma unroll
            for (int w2 = 1; w2 < 4; ++w2) {
                const float m2 = scr[(w2 * 128 + row) * 2 + 0];
                const float l2 = scr[(w2 * 128 + row) * 2 + 1];
                const float mm = fmaxf(m, m2);
                l = l * __expf(m - mm) + l2 * __expf(m2 - mm);
                m = mm;
            }
            m_r[mf][r] = m;
            l_r[mf][r] = 1.0f / l;     // l_r now holds 1/l
        }
    __syncthreads();   // scr reads done; PB free for pass B

    // -------- pass B: recompute, write attn, accumulate PV --------
    const f32x4 zero = {0.f, 0.f, 0.f, 0.f};
    f32x4 pv[4];
#pragma unroll
    for (int i = 0; i < 4; ++i) pv[i] = zero;

    pkh0 = *(const bf16x8*)(Kh_ + (size_t)r0 * 64 + kc8);
    pkh1 = *(const bf16x8*)(Kh_ + (size_t)(r0 + 64) * 64 + kc8);
    pkl0 = *(const bf16x8*)(Kl_ + (size_t)r0 * 64 + kc8);
    pkl1 = *(const bf16x8*)(Kl_ + (size_t)(r0 + 64) * 64 + kc8);

    for (int t = 0; t < 16; ++t) {
        __syncthreads();                          // prev tile PV done: KV, PB free
        *(bf16x8*)(KV + lk0) = pkh0; *(bf16x8*)(KV + lk1) = pkh1;
        *(bf16x8*)(KV + 16384 + lk0) = pkl0; *(bf16x8*)(KV + 16384 + lk1) = pkl1;
        __syncthreads();
        // issue this-tile V and next-tile K loads early (hide under compute)
        bf16x8 vh0, vh1, vl0, vl1;
        {
            const size_t gv = (size_t)r0 * S_LEN + t * 128;
            vh0 = *(const bf16x8*)(Vh_ + gv + kc8);
            vh1 = *(const bf16x8*)(Vh_ + gv + kc8 + 64);
            vl0 = *(const bf16x8*)(Vl_ + gv + kc8);
            vl1 = *(const bf16x8*)(Vl_ + gv + kc8 + 64);
        }
        if (t < 15) {
            const size_t g = (size_t)((t + 1) * 128) * 64 + kc8;
            pkh0 = *(const bf16x8*)(Kh_ + g + (size_t)r0 * 64);
            pkh1 = *(const bf16x8*)(Kh_ + g + (size_t)(r0 + 64) * 64);
            pkl0 = *(const bf16x8*)(Kl_ + g + (size_t)r0 * 64);
            pkl1 = *(const bf16x8*)(Kl_ + g + (size_t)(r0 + 64) * 64);
        }
        f32x4 acc[4][2];
        qk_tile(acc);
        // p = exp(s - m) * (1/l) ; write attn
#pragma unroll
        for (int mf = 0; mf < 4; ++mf) {
            const int rg0 = bm + wm * 64 + mf * 16 + (lane >> 4) * 4;
#pragma unroll
            for (int nf = 0; nf < 2; ++nf) {
                const int col = t * 128 + wn * 32 + nf * 16 + (lane & 15);
#pragma unroll
                for (int r = 0; r < 4; ++r) {
                    const float p = __expf(acc[mf][nf][r] - m_r[mf][r]) * l_r[mf][r];
                    acc[mf][nf][r] = p;
                    attn_b[(size_t)(rg0 + r) * S_LEN + col] = p;
                }
            }
        }
        __syncthreads();                          // K reads done -> KV reusable for V
        *(bf16x8*)(KV + lv0) = vh0; *(bf16x8*)(KV + lv1) = vh1;
        *(bf16x8*)(KV + 16384 + lv0) = vl0; *(bf16x8*)(KV + 16384 + lv1) = vl1;
        // store P half-0 (cols 0..63, owned by waves wn<2)
        if (wn < 2) {
#pragma unroll
            for (int mf = 0; mf < 4; ++mf)
#pragma unroll
                for (int nf = 0; nf < 2; ++nf) {
                    const int k = (wn & 1) * 32 + nf * 16 + (lane & 15);
#pragma unroll
                    for (int r = 0; r < 4; ++r) {
                        const int rl = wm * 64 + mf * 16 + (lane >> 4) * 4 + r;
                        const int off = (((rl >> 4) * 2 + (k >> 5)) << 10) +
                                        (((k >> 3) & 3) << 8) + ((rl & 15) << 4) + ((k & 7) << 1);
                        __bf16 h, l;
                        split2(acc[mf][nf][r], h, l);
                        *(__bf16*)(PB + off) = h;
                        *(__bf16*)(PB + 16384 + off) = l;
                    }
                }
        }
        __syncthreads();                          // V + P half-0 visible
#pragma unroll
        for (int kf = 0; kf < 2; ++kf) {
            const int offv = ((wn * 4 + 0 + kf) << 10) + lane * 16;
            const bf16x8 vhf = *(const bf16x8*)(KV + offv);
            const bf16x8 vlf = *(const bf16x8*)(KV + 16384 + offv);
#pragma unroll
            for (int mf = 0; mf < 4; ++mf) {
                const int offp = (((wm * 4 + mf) * 2 + kf) << 10) + lane * 16;
                const bf16x8 ph = *(const bf16x8*)(PB + offp);
                const bf16x8 pl = *(const bf16x8*)(PB + 16384 + offp);
                pv[mf] = mm16(pl, vhf, pv[mf]);
                pv[mf] = mm16(ph, vlf, pv[mf]);
                pv[mf] = mm16(ph, vhf, pv[mf]);
            }
        }
        __syncthreads();                          // P half-0 reads done
        // store P half-1 (cols 64..127, owned by waves wn>=2)
        if (wn >= 2) {
#pragma unroll
            for (int mf = 0; mf < 4; ++mf)
#pragma unroll
                for (int nf = 0; nf < 2; ++nf) {
                    const int k = (wn & 1) * 32 + nf * 16 + (lane & 15);
#pragma unroll
                    for (int r = 0; r < 4; ++r) {
                        const int rl = wm * 64 + mf * 16 + (lane >> 4) * 4 + r;
                        const int off = (((rl >> 4) * 2 + (k >> 5)) << 10) +
                                        (((k >> 3) & 3) << 8) + ((rl & 15) << 4) + ((k & 7) << 1);
                        __bf16 h, l;
                        split2(acc[mf][nf][r], h, l);
                        *(__bf16*)(PB + off) = h;
                        *(__bf16*)(PB + 16384 + off) = l;
                    }
                }
        }
        __syncthreads();                          // P half-1 visible
#pragma unroll
        for (int kf = 0; kf < 2; ++kf) {
            const int offv = ((wn * 4 + 2 + kf) << 10) + lane * 16;
            const bf16x8 vhf = *(const bf16x8*)(KV + offv);
            const bf16x8 vlf = *(const bf16x8*)(KV + 16384 + offv);
#pragma unroll
            for (int mf = 0; mf < 4; ++mf) {
                const int offp = (((wm * 4 + mf) * 2 + kf) << 10) + lane * 16;
                const bf16x8 ph = *(const bf16x8*)(PB + offp);
                const bf16x8 pl = *(const bf16x8*)(PB + 16384 + offp);
                pv[mf] = mm16(pl, vhf, pv[mf]);
                pv[mf] = mm16(ph, vlf, pv[mf]);
                pv[mf] = mm16(ph, vhf, pv[mf]);
            }
        }
    }

    // ctx epilogue: [s][1024] fp32, head slice
#pragma unroll
    for (int mf = 0; mf < 4; ++mf)
#pragma unroll
        for (int r = 0; r < 4; ++r) {
            const int sg = bm + wm * 64 + mf * 16 + (lane >> 4) * 4 + r;
            const int d = wn * 16 + (lane & 15);
            ctxb[(size_t)sg * 1024 + bh * 64 + d] = pv[mf][r];
        }
}

// ---------------------------------------------------------------------------
extern "C" void kernel_launch(void* const* d_in, const int* in_sizes, int n_in,
                              void* d_out, int out_size, void* d_ws, size_t ws_size,
                              hipStream_t stream)
{
    const float* q  = (const float*)d_in[0];
    const float* k  = (const float*)d_in[1];
    const float* v  = (const float*)d_in[2];
    const float* wq = (const float*)d_in[3];
    const float* bq = (const float*)d_in[4];
    const float* wk = (const float*)d_in[5];
    const float* bk = (const float*)d_in[6];
    const float* wv = (const float*)d_in[7];
    const float* bv = (const float*)d_in[8];
    const float* wo = (const float*)d_in[9];
    const float* bo = (const float*)d_in[10];

    float* out  = (float*)d_out;                          // [2,2048,1024]
    float* attn = out + (size_t)BATCH * S_LEN * D_MODEL;  // [2,16,2048,2048]

    // workspace (64 MB):
    //  0- 4: woT hi/lo | 4-16: wqT,wkT,wvT hi/lo (dead after projections)
    //  4-12: ctxb fp32 (per-batch, reuses wq/wk region)
    // 16-32: Q hi/lo | 32-48: K hi/lo | 48-64: Vt hi/lo
    char* ws = (char*)d_ws;
    const size_t MB = 1024 * 1024;
    __bf16* WB   = (__bf16*)ws;
    __bf16* QHI  = (__bf16*)(ws + 16 * MB);
    __bf16* QLO  = (__bf16*)(ws + 24 * MB);
    __bf16* KHI  = (__bf16*)(ws + 32 * MB);
    __bf16* KLO  = (__bf16*)(ws + 40 * MB);
    __bf16* VTHI = (__bf16*)(ws + 48 * MB);
    __bf16* VTLO = (__bf16*)(ws + 56 * MB);
    float*  ctxb = (float*)(ws + 4 * MB);

    const size_t W1M = 1048576;   // elems in 2 MB of bf16
    __bf16* WOT_HI = WB;                  __bf16* WOT_LO = WB + W1M;
    __bf16* WQT_HI = WB + 2 * W1M;        __bf16* WQT_LO = WB + 3 * W1M;
    __bf16* WKT_HI = WB + 4 * W1M;        __bf16* WKT_LO = WB + 5 * W1M;
    __bf16* WVT_HI = WB + 6 * W1M;        __bf16* WVT_LO = WB + 7 * W1M;

    wsplit<<<dim3(16, 16, 4), dim3(256), 0, stream>>>(wq, wk, wv, wo, WB);

    // projections (Q pre-scaled by 1/8 via mode 3)
    gemm_split<<<dim3(32, 8), dim3(512), 0, stream>>>(q, WQT_HI, WQT_LO, bq, QHI, QLO, nullptr, 3);
    gemm_split<<<dim3(32, 8), dim3(512), 0, stream>>>(k, WKT_HI, WKT_LO, bk, KHI, KLO, nullptr, 0);
    gemm_split<<<dim3(32, 8), dim3(512), 0, stream>>>(v, WVT_HI, WVT_LO, bv, VTHI, VTLO, nullptr, 2);

    const size_t HOFF = (size_t)NUM_HEADS * S_LEN * DEPTH;  // per-batch elems
    for (int b = 0; b < BATCH; ++b) {
        attn_fused<<<dim3(256), dim3(512), 0, stream>>>(
            QHI + b * HOFF, QLO + b * HOFF, KHI + b * HOFF, KLO + b * HOFF,
            VTHI + b * HOFF, VTLO + b * HOFF,
            attn + (size_t)b * NUM_HEADS * S_LEN * S_LEN, ctxb);
        gemm_split<<<dim3(16, 8), dim3(512), 0, stream>>>(
            ctxb, WOT_HI, WOT_LO, bo, nullptr, nullptr,
            out + (size_t)b * S_LEN * D_MODEL, 1);
    }
}

// Round 4
// 1048.067 us; speedup vs baseline: 1.6643x; 1.0362x over previous
//
#include <hip/hip_runtime.h>
#include <math.h>

#define D_MODEL   1024
#define NUM_HEADS 16
#define DEPTH     64
#define S_LEN     2048
#define BATCH     2

typedef __attribute__((ext_vector_type(4))) float  f32x4;
typedef __attribute__((ext_vector_type(8))) __bf16 bf16x8;
typedef __attribute__((ext_vector_type(4))) __bf16 bf16x4;

#if __has_builtin(__builtin_amdgcn_exp2f)
#define E2(x) __builtin_amdgcn_exp2f(x)
#else
#define E2(x) exp2f(x)
#endif

// LDS-only barrier: all staging is reg-staged (lgkm covers ds_write/ds_read);
// global stores are never re-read in-kernel, so no vmcnt drain needed.
// sched_barrier(0) fences compiler motion across the barrier (guide rule #18).
__device__ __forceinline__ void bar() {
    asm volatile("s_waitcnt lgkmcnt(0)" ::: "memory");
    __builtin_amdgcn_s_barrier();
    __builtin_amdgcn_sched_barrier(0);
}

// fp32 -> bf16 hi/lo split: x ~= hi + lo with ~2^-18 relative residual.
__device__ __forceinline__ void split2(float x, __bf16& h, __bf16& l) {
    h = (__bf16)x;
    l = (__bf16)(x - (float)h);
}

// fragment-ordered LDS byte offset; tile = [rows][kwidth] bf16.
// fragment (r>>4, k>>5) is 1 KiB; lane slot = ((k>>3)&3)*16 + (r&15); 16B/slot.
__device__ __forceinline__ int frag2(int r, int k) {   // kwidth 64
    return (((r >> 4) * 2 + (k >> 5)) << 10) + (((k >> 3) & 3) << 8) + ((r & 15) << 4);
}
__device__ __forceinline__ int frag4(int r, int k) {   // kwidth 128
    return (((r >> 4) * 4 + (k >> 5)) << 10) + (((k >> 3) & 3) << 8) + ((r & 15) << 4);
}

__device__ __forceinline__ f32x4 mm16(bf16x8 a, bf16x8 b, f32x4 c) {
    return __builtin_amdgcn_mfma_f32_16x16x32_bf16(a, b, c, 0, 0, 0);
}

__device__ __forceinline__ void split8(f32x4 x0, f32x4 x1, bf16x8& vh, bf16x8& vl) {
#pragma unroll
    for (int j = 0; j < 4; ++j) {
        __bf16 h, l;
        split2(x0[j], h, l); vh[j] = h;     vl[j] = l;
        split2(x1[j], h, l); vh[j + 4] = h; vl[j + 4] = l;
    }
}

// ---------------------------------------------------------------------------
// Weight prep: W[k][n] fp32 -> Wt_hi/Wt_lo[n][k] bf16 (transpose + split).
// Layout in WB (elems of 1M): wo hi@0 lo@1; wq hi@2 lo@3; wk hi@4 lo@5; wv hi@6 lo@7.
// ---------------------------------------------------------------------------
__global__ __launch_bounds__(256) void wsplit(const float* __restrict__ w0,
                                              const float* __restrict__ w1,
                                              const float* __restrict__ w2,
                                              const float* __restrict__ w3,
                                              __bf16* __restrict__ base)
{
    const int z = blockIdx.z;
    const float* W = (z == 0) ? w0 : (z == 1) ? w1 : (z == 2) ? w2 : w3;
    const size_t hi_off = (z == 3) ? 0 : (size_t)(z + 1) * 2097152;
    __bf16* Hi = base + hi_off;
    __bf16* Lo = Hi + 1048576;

    __shared__ float T[64][65];
    const int tid = threadIdx.x;
    const int k0 = blockIdx.x * 64, n0 = blockIdx.y * 64;
    const int rr = tid / 16, cc = (tid % 16) * 4;

#pragma unroll
    for (int p = 0; p < 4; ++p) {
        int r = p * 16 + rr;
        f32x4 v = *(const f32x4*)&W[(size_t)(k0 + r) * 1024 + n0 + cc];
        T[r][cc + 0] = v[0]; T[r][cc + 1] = v[1];
        T[r][cc + 2] = v[2]; T[r][cc + 3] = v[3];
    }
    __syncthreads();
#pragma unroll
    for (int p = 0; p < 4; ++p) {
        int nr = p * 16 + rr;
        bf16x4 vh, vl;
#pragma unroll
        for (int j = 0; j < 4; ++j) {
            __bf16 h, l;
            split2(T[cc + j][nr], h, l);
            vh[j] = h; vl[j] = l;
        }
        *(bf16x4*)&Hi[(size_t)(n0 + nr) * 1024 + k0 + cc] = vh;
        *(bf16x4*)&Lo[(size_t)(n0 + nr) * 1024 + k0 + cc] = vl;
    }
}

// ---------------------------------------------------------------------------
// Merged QKV projection. blockIdx.z: 0=Q (scale folds 0.125*log2e), 1=K, 2=V.
// C = X * WT^T + b. Tile 128x128, BK=64, 512 thr (8 waves 2x4).
// Q/K: bf16 hi/lo head-split [bh][s][d]. V: bf16 hi/lo transposed [bh][d][s].
// ---------------------------------------------------------------------------
__global__ __launch_bounds__(512) void qkv_proj(
    const float* __restrict__ qi, const float* __restrict__ ki, const float* __restrict__ vi,
    const __bf16* __restrict__ WB,
    const float* __restrict__ bq, const float* __restrict__ bk, const float* __restrict__ bv,
    __bf16* __restrict__ QHI, __bf16* __restrict__ QLO,
    __bf16* __restrict__ KHI, __bf16* __restrict__ KLO,
    __bf16* __restrict__ VTHI, __bf16* __restrict__ VTLO)
{
    const int z = blockIdx.z;
    const float* A = (z == 0) ? qi : (z == 1) ? ki : vi;
    const __bf16* BtHi = WB + (size_t)(2 + 2 * z) * 1048576;
    const __bf16* BtLo = BtHi + 1048576;
    const float* bias = (z == 0) ? bq : (z == 1) ? bk : bv;
    __bf16* oHi = (z == 0) ? QHI : (z == 1) ? KHI : VTHI;
    __bf16* oLo = (z == 0) ? QLO : (z == 1) ? KLO : VTLO;
    const float scale = (z == 0) ? 0.18033688f : 1.0f;   // 0.125 * log2(e) for Q

    __shared__ __align__(16) char lds[65536];
    char* AH = lds;
    char* AL = lds + 16384;
    char* BH = lds + 32768;
    char* BL = lds + 49152;

    const int tid = threadIdx.x;
    const int lane = tid & 63, wid = tid >> 6;
    const int wm = wid >> 2, wn = wid & 3;
    const int bm = blockIdx.x * 128, bn = blockIdx.y * 128;

    const int r0 = tid >> 3, kc8 = (tid & 7) * 8;
    const int r1 = r0 + 64;
    const size_t a0 = (size_t)(bm + r0) * 1024 + kc8;
    const size_t a1 = (size_t)(bm + r1) * 1024 + kc8;
    const size_t b0 = (size_t)(bn + r0) * 1024 + kc8;
    const size_t b1 = (size_t)(bn + r1) * 1024 + kc8;
    const int la0 = frag2(r0, kc8), la1 = frag2(r1, kc8);

    const f32x4 zero = {0.f, 0.f, 0.f, 0.f};
    f32x4 acc[4][2];
#pragma unroll
    for (int i = 0; i < 4; ++i) { acc[i][0] = zero; acc[i][1] = zero; }

    f32x4 x0 = *(const f32x4*)(A + a0), x1 = *(const f32x4*)(A + a0 + 4);
    f32x4 x2 = *(const f32x4*)(A + a1), x3 = *(const f32x4*)(A + a1 + 4);
    bf16x8 bh0 = *(const bf16x8*)(BtHi + b0);
    bf16x8 bh1 = *(const bf16x8*)(BtHi + b1);
    bf16x8 bl0 = *(const bf16x8*)(BtLo + b0);
    bf16x8 bl1 = *(const bf16x8*)(BtLo + b1);

    for (int k0 = 0; k0 < 1024; k0 += 64) {
        bf16x8 ah0, al0, ah1, al1;
        split8(x0, x1, ah0, al0);
        split8(x2, x3, ah1, al1);
        bar();
        *(bf16x8*)(AH + la0) = ah0; *(bf16x8*)(AL + la0) = al0;
        *(bf16x8*)(AH + la1) = ah1; *(bf16x8*)(AL + la1) = al1;
        *(bf16x8*)(BH + la0) = bh0; *(bf16x8*)(BH + la1) = bh1;
        *(bf16x8*)(BL + la0) = bl0; *(bf16x8*)(BL + la1) = bl1;
        bar();
        if (k0 + 64 < 1024) {
            const int kn = k0 + 64;
            x0 = *(const f32x4*)(A + a0 + kn); x1 = *(const f32x4*)(A + a0 + kn + 4);
            x2 = *(const f32x4*)(A + a1 + kn); x3 = *(const f32x4*)(A + a1 + kn + 4);
            bh0 = *(const bf16x8*)(BtHi + b0 + kn);
            bh1 = *(const bf16x8*)(BtHi + b1 + kn);
            bl0 = *(const bf16x8*)(BtLo + b0 + kn);
            bl1 = *(const bf16x8*)(BtLo + b1 + kn);
        }
#pragma unroll
        for (int kf = 0; kf < 2; ++kf) {
            bf16x8 fah[4], fal[4], fbh[2], fbl[2];
#pragma unroll
            for (int mf = 0; mf < 4; ++mf) {
                const int off = (((wm * 4 + mf) * 2 + kf) << 10) + lane * 16;
                fah[mf] = *(const bf16x8*)(AH + off);
                fal[mf] = *(const bf16x8*)(AL + off);
            }
#pragma unroll
            for (int nf = 0; nf < 2; ++nf) {
                const int off = (((wn * 2 + nf) * 2 + kf) << 10) + lane * 16;
                fbh[nf] = *(const bf16x8*)(BH + off);
                fbl[nf] = *(const bf16x8*)(BL + off);
            }
#pragma unroll
            for (int mf = 0; mf < 4; ++mf)
#pragma unroll
                for (int nf = 0; nf < 2; ++nf) {
                    acc[mf][nf] = mm16(fal[mf], fbh[nf], acc[mf][nf]);
                    acc[mf][nf] = mm16(fah[mf], fbl[nf], acc[mf][nf]);
                    acc[mf][nf] = mm16(fah[mf], fbh[nf], acc[mf][nf]);
                }
        }
    }

    const int rbase = (lane >> 4) * 4;
    const int cloc = lane & 15;
#pragma unroll
    for (int mf = 0; mf < 4; ++mf) {
        const int m0g = bm + wm * 64 + mf * 16 + rbase;
#pragma unroll
        for (int nf = 0; nf < 2; ++nf) {
            const int n_g = bn + wn * 32 + nf * 16 + cloc;
            const float bv2 = bias[n_g];
            float v[4];
#pragma unroll
            for (int r = 0; r < 4; ++r) v[r] = (acc[mf][nf][r] + bv2) * scale;
            const int bb = m0g >> 11;
            const int sloc = m0g & 2047;
            const int h = n_g >> 6, d = n_g & 63;
            if (z != 2) {   // Q/K: head-split [bh][s][d]
                const size_t i0 = ((size_t)(bb * 16 + h) * 2048 + sloc) * 64 + d;
#pragma unroll
                for (int r = 0; r < 4; ++r) {
                    __bf16 hh, ll;
                    split2(v[r], hh, ll);
                    oHi[i0 + (size_t)r * 64] = hh;
                    oLo[i0 + (size_t)r * 64] = ll;
                }
            } else {        // V: Vt[bh][d][s]
                const size_t i0 = ((size_t)(bb * 16 + h) * 64 + d) * 2048 + sloc;
                bf16x4 vh, vl;
#pragma unroll
                for (int r = 0; r < 4; ++r) {
                    __bf16 hh, ll;
                    split2(v[r], hh, ll);
                    vh[r] = hh; vl[r] = ll;
                }
                *(bf16x4*)&oHi[i0] = vh;
                *(bf16x4*)&oLo[i0] = vl;
            }
        }
    }
}

// ---------------------------------------------------------------------------
// Output projection: out = ctx[4096,1024] @ woT^T + bo, fp32 in/out.
// ---------------------------------------------------------------------------
__global__ __launch_bounds__(512) void out_proj(
    const float* __restrict__ A,
    const __bf16* __restrict__ BtHi, const __bf16* __restrict__ BtLo,
    const float* __restrict__ bias, float* __restrict__ oF)
{
    __shared__ __align__(16) char lds[65536];
    char* AH = lds;
    char* AL = lds + 16384;
    char* BH = lds + 32768;
    char* BL = lds + 49152;

    const int tid = threadIdx.x;
    const int lane = tid & 63, wid = tid >> 6;
    const int wm = wid >> 2, wn = wid & 3;
    const int bm = blockIdx.x * 128, bn = blockIdx.y * 128;

    const int r0 = tid >> 3, kc8 = (tid & 7) * 8;
    const int r1 = r0 + 64;
    const size_t a0 = (size_t)(bm + r0) * 1024 + kc8;
    const size_t a1 = (size_t)(bm + r1) * 1024 + kc8;
    const size_t b0 = (size_t)(bn + r0) * 1024 + kc8;
    const size_t b1 = (size_t)(bn + r1) * 1024 + kc8;
    const int la0 = frag2(r0, kc8), la1 = frag2(r1, kc8);

    const f32x4 zero = {0.f, 0.f, 0.f, 0.f};
    f32x4 acc[4][2];
#pragma unroll
    for (int i = 0; i < 4; ++i) { acc[i][0] = zero; acc[i][1] = zero; }

    f32x4 x0 = *(const f32x4*)(A + a0), x1 = *(const f32x4*)(A + a0 + 4);
    f32x4 x2 = *(const f32x4*)(A + a1), x3 = *(const f32x4*)(A + a1 + 4);
    bf16x8 bh0 = *(const bf16x8*)(BtHi + b0);
    bf16x8 bh1 = *(const bf16x8*)(BtHi + b1);
    bf16x8 bl0 = *(const bf16x8*)(BtLo + b0);
    bf16x8 bl1 = *(const bf16x8*)(BtLo + b1);

    for (int k0 = 0; k0 < 1024; k0 += 64) {
        bf16x8 ah0, al0, ah1, al1;
        split8(x0, x1, ah0, al0);
        split8(x2, x3, ah1, al1);
        bar();
        *(bf16x8*)(AH + la0) = ah0; *(bf16x8*)(AL + la0) = al0;
        *(bf16x8*)(AH + la1) = ah1; *(bf16x8*)(AL + la1) = al1;
        *(bf16x8*)(BH + la0) = bh0; *(bf16x8*)(BH + la1) = bh1;
        *(bf16x8*)(BL + la0) = bl0; *(bf16x8*)(BL + la1) = bl1;
        bar();
        if (k0 + 64 < 1024) {
            const int kn = k0 + 64;
            x0 = *(const f32x4*)(A + a0 + kn); x1 = *(const f32x4*)(A + a0 + kn + 4);
            x2 = *(const f32x4*)(A + a1 + kn); x3 = *(const f32x4*)(A + a1 + kn + 4);
            bh0 = *(const bf16x8*)(BtHi + b0 + kn);
            bh1 = *(const bf16x8*)(BtHi + b1 + kn);
            bl0 = *(const bf16x8*)(BtLo + b0 + kn);
            bl1 = *(const bf16x8*)(BtLo + b1 + kn);
        }
#pragma unroll
        for (int kf = 0; kf < 2; ++kf) {
            bf16x8 fah[4], fal[4], fbh[2], fbl[2];
#pragma unroll
            for (int mf = 0; mf < 4; ++mf) {
                const int off = (((wm * 4 + mf) * 2 + kf) << 10) + lane * 16;
                fah[mf] = *(const bf16x8*)(AH + off);
                fal[mf] = *(const bf16x8*)(AL + off);
            }
#pragma unroll
            for (int nf = 0; nf < 2; ++nf) {
                const int off = (((wn * 2 + nf) * 2 + kf) << 10) + lane * 16;
                fbh[nf] = *(const bf16x8*)(BH + off);
                fbl[nf] = *(const bf16x8*)(BL + off);
            }
#pragma unroll
            for (int mf = 0; mf < 4; ++mf)
#pragma unroll
                for (int nf = 0; nf < 2; ++nf) {
                    acc[mf][nf] = mm16(fal[mf], fbh[nf], acc[mf][nf]);
                    acc[mf][nf] = mm16(fah[mf], fbl[nf], acc[mf][nf]);
                    acc[mf][nf] = mm16(fah[mf], fbh[nf], acc[mf][nf]);
                }
        }
    }

    const int rbase = (lane >> 4) * 4;
    const int cloc = lane & 15;
#pragma unroll
    for (int mf = 0; mf < 4; ++mf) {
        const int m0g = bm + wm * 64 + mf * 16 + rbase;
#pragma unroll
        for (int nf = 0; nf < 2; ++nf) {
            const int n_g = bn + wn * 32 + nf * 16 + cloc;
            const float bv2 = bias[n_g];
#pragma unroll
            for (int r = 0; r < 4; ++r)
                oF[(size_t)(m0g + r) * 1024 + n_g] = acc[mf][nf][r] + bv2;
        }
    }
}

// ---------------------------------------------------------------------------
// Fused flash attention, BOTH batches in one launch (512 blocks).
// Block = 128 Q-rows of one (b,h). 512 thr = 8 waves (2 wm x 4 wn).
// Scores are in log2-domain (Q pre-scaled by 0.125*log2e): p = 2^(s-m)/l.
// Pass A: QK^T -> online (m,l) with defer-max THR=8.  Pass B: recompute QK^T,
// write normalized attn (fp32, exactly once), stage P hi/lo in LDS, accumulate
// PV -> ctx (fp32, written into the `out` region of d_out).
// ---------------------------------------------------------------------------
__global__ __launch_bounds__(512) void attn_fused(
    const __bf16* __restrict__ QHi, const __bf16* __restrict__ QLo,
    const __bf16* __restrict__ KHi, const __bf16* __restrict__ KLo,
    const __bf16* __restrict__ VtHi, const __bf16* __restrict__ VtLo,
    float* __restrict__ attn, float* __restrict__ ctx)
{
    __shared__ __align__(16) char lds[65536];
    char* KV = lds;            // hi @0, lo @16384
    char* PB = lds + 32768;    // hi @0, lo @16384 ; pass A: (m,l) scratch
    float* scr = (float*)PB;   // [4 wn][128 rows][2]

    const int tid = threadIdx.x;
    const int lane = tid & 63, wid = tid >> 6;
    const int wm = wid >> 2, wn = wid & 3;

    // XCD swizzle: id%8 = XCD; each XCD owns 4 consecutive bh groups (16 q-tiles
    // each) -> K/V (1 MB/bh) L2-resident per XCD.
    const int id = blockIdx.x;                 // 0..511
    const int bh = (id & 7) * 4 + (id >> 7);   // 0..31 = b*16+h
    const int bm = ((id >> 3) & 15) * 128;     // q-tile

    const __bf16* Qh_ = QHi + (size_t)bh * S_LEN * 64;
    const __bf16* Ql_ = QLo + (size_t)bh * S_LEN * 64;
    const __bf16* Kh_ = KHi + (size_t)bh * S_LEN * 64;
    const __bf16* Kl_ = KLo + (size_t)bh * S_LEN * 64;
    const __bf16* Vh_ = VtHi + (size_t)bh * 64 * S_LEN;
    const __bf16* Vl_ = VtLo + (size_t)bh * 64 * S_LEN;
    float* attn_b = attn + (size_t)bh * S_LEN * S_LEN;

    // Q fragments in registers
    bf16x8 qh[4][2], ql[4][2];
#pragma unroll
    for (int mf = 0; mf < 4; ++mf)
#pragma unroll
        for (int kf = 0; kf < 2; ++kf) {
            const int row = bm + wm * 64 + mf * 16 + (lane & 15);
            const int k = kf * 32 + (lane >> 4) * 8;
            qh[mf][kf] = *(const bf16x8*)(Qh_ + (size_t)row * 64 + k);
            ql[mf][kf] = *(const bf16x8*)(Ql_ + (size_t)row * 64 + k);
        }

    const int r0 = tid >> 3, kc8 = (tid & 7) * 8;
    const int lk0 = frag2(r0, kc8), lk1 = frag2(r0 + 64, kc8);
    const int lv0 = frag4(r0, kc8), lv1 = frag4(r0, kc8 + 64);

    auto qk_tile = [&](f32x4 (&acc)[4][2]) {
        const f32x4 z4 = {0.f, 0.f, 0.f, 0.f};
#pragma unroll
        for (int i = 0; i < 4; ++i) { acc[i][0] = z4; acc[i][1] = z4; }
#pragma unroll
        for (int kf = 0; kf < 2; ++kf) {
            bf16x8 kbh[2], kbl[2];
#pragma unroll
            for (int nf = 0; nf < 2; ++nf) {
                const int off = (((wn * 2 + nf) * 2 + kf) << 10) + lane * 16;
                kbh[nf] = *(const bf16x8*)(KV + off);
                kbl[nf] = *(const bf16x8*)(KV + 16384 + off);
            }
#pragma unroll
            for (int mf = 0; mf < 4; ++mf)
#pragma unroll
                for (int nf = 0; nf < 2; ++nf) {
                    acc[mf][nf] = mm16(ql[mf][kf], kbh[nf], acc[mf][nf]);
                    acc[mf][nf] = mm16(qh[mf][kf], kbl[nf], acc[mf][nf]);
                    acc[mf][nf] = mm16(qh[mf][kf], kbh[nf], acc[mf][nf]);
                }
        }
    };

    float m_r[4][4], l_r[4][4];
#pragma unroll
    for (int mf = 0; mf < 4; ++mf)
#pragma unroll
        for (int r = 0; r < 4; ++r) { m_r[mf][r] = -INFINITY; l_r[mf][r] = 0.f; }

    // -------- pass A: online (m,l), defer-max THR=8 --------
    bf16x8 pkh0 = *(const bf16x8*)(Kh_ + (size_t)r0 * 64 + kc8);
    bf16x8 pkh1 = *(const bf16x8*)(Kh_ + (size_t)(r0 + 64) * 64 + kc8);
    bf16x8 pkl0 = *(const bf16x8*)(Kl_ + (size_t)r0 * 64 + kc8);
    bf16x8 pkl1 = *(const bf16x8*)(Kl_ + (size_t)(r0 + 64) * 64 + kc8);

    for (int t = 0; t < 16; ++t) {
        bar();
        *(bf16x8*)(KV + lk0) = pkh0; *(bf16x8*)(KV + lk1) = pkh1;
        *(bf16x8*)(KV + 16384 + lk0) = pkl0; *(bf16x8*)(KV + 16384 + lk1) = pkl1;
        bar();
        if (t < 15) {
            const size_t g = (size_t)((t + 1) * 128) * 64 + kc8;
            pkh0 = *(const bf16x8*)(Kh_ + g + (size_t)r0 * 64);
            pkh1 = *(const bf16x8*)(Kh_ + g + (size_t)(r0 + 64) * 64);
            pkl0 = *(const bf16x8*)(Kl_ + g + (size_t)r0 * 64);
            pkl1 = *(const bf16x8*)(Kl_ + g + (size_t)(r0 + 64) * 64);
        }
        f32x4 acc[4][2];
        qk_tile(acc);
        int ok = 1;
#pragma unroll
        for (int mf = 0; mf < 4; ++mf)
#pragma unroll
            for (int r = 0; r < 4; ++r)
                ok &= (fmaxf(acc[mf][0][r], acc[mf][1][r]) <= m_r[mf][r] + 8.0f);
        if (__all(ok)) {
            // max stable within THR: no rescale, terms bounded by 2^8
#pragma unroll
            for (int mf = 0; mf < 4; ++mf)
#pragma unroll
                for (int r = 0; r < 4; ++r)
                    l_r[mf][r] += E2(acc[mf][0][r] - m_r[mf][r]) +
                                  E2(acc[mf][1][r] - m_r[mf][r]);
        } else {
#pragma unroll
            for (int mf = 0; mf < 4; ++mf)
#pragma unroll
                for (int r = 0; r < 4; ++r) {
                    const float s0 = acc[mf][0][r], s1 = acc[mf][1][r];
                    const float mo = m_r[mf][r];
                    const float mn = fmaxf(mo, fmaxf(s0, s1));
                    l_r[mf][r] = l_r[mf][r] * E2(mo - mn) + E2(s0 - mn) + E2(s1 - mn);
                    m_r[mf][r] = mn;
                }
        }
    }

    // butterfly over the 16-lane col groups
#pragma unroll
    for (int mf = 0; mf < 4; ++mf)
#pragma unroll
        for (int r = 0; r < 4; ++r) {
            float m = m_r[mf][r], l = l_r[mf][r];
#pragma unroll
            for (int mask = 1; mask < 16; mask <<= 1) {
                const float m2 = __shfl_xor(m, mask);
                const float l2 = __shfl_xor(l, mask);
                const float mm = fmaxf(m, m2);
                l = l * E2(m - mm) + l2 * E2(m2 - mm);
                m = mm;
            }
            m_r[mf][r] = m; l_r[mf][r] = l;
        }
    // cross-wave (4 wn waves share rows) via LDS scratch
    if ((lane & 15) == 0) {
#pragma unroll
        for (int mf = 0; mf < 4; ++mf)
#pragma unroll
            for (int r = 0; r < 4; ++r) {
                const int row = wm * 64 + mf * 16 + (lane >> 4) * 4 + r;
                scr[(wn * 128 + row) * 2 + 0] = m_r[mf][r];
                scr[(wn * 128 + row) * 2 + 1] = l_r[mf][r];
            }
    }
    bar();
#pragma unroll
    for (int mf = 0; mf < 4; ++mf)
#pragma unroll
        for (int r = 0; r < 4; ++r) {
            const int row = wm * 64 + mf * 16 + (lane >> 4) * 4 + r;
            float m = scr[row * 2 + 0], l = scr[row * 2 + 1];
#pragma unroll
            for (int w2 = 1; w2 < 4; ++w2) {
                const float m2 = scr[(w2 * 128 + row) * 2 + 0];
                const float l2 = scr[(w2 * 128 + row) * 2 + 1];
                const float mm = fmaxf(m, m2);
                l = l * E2(m - mm) + l2 * E2(m2 - mm);
                m = mm;
            }
            m_r[mf][r] = m;
            l_r[mf][r] = 1.0f / l;     // l_r now holds 1/l
        }
    bar();   // scr reads done; PB free for pass B

    // -------- pass B: recompute, write attn, accumulate PV --------
    const f32x4 zero = {0.f, 0.f, 0.f, 0.f};
    f32x4 pv[4];
#pragma unroll
    for (int i = 0; i < 4; ++i) pv[i] = zero;

    pkh0 = *(const bf16x8*)(Kh_ + (size_t)r0 * 64 + kc8);
    pkh1 = *(const bf16x8*)(Kh_ + (size_t)(r0 + 64) * 64 + kc8);
    pkl0 = *(const bf16x8*)(Kl_ + (size_t)r0 * 64 + kc8);
    pkl1 = *(const bf16x8*)(Kl_ + (size_t)(r0 + 64) * 64 + kc8);

    for (int t = 0; t < 16; ++t) {
        bar();                                    // prev tile PV done: KV, PB free
        *(bf16x8*)(KV + lk0) = pkh0; *(bf16x8*)(KV + lk1) = pkh1;
        *(bf16x8*)(KV + 16384 + lk0) = pkl0; *(bf16x8*)(KV + 16384 + lk1) = pkl1;
        bar();
        // issue this-tile V and next-tile K loads early (stay in flight across bars)
        bf16x8 vh0, vh1, vl0, vl1;
        {
            const size_t gv = (size_t)r0 * S_LEN + t * 128;
            vh0 = *(const bf16x8*)(Vh_ + gv + kc8);
            vh1 = *(const bf16x8*)(Vh_ + gv + kc8 + 64);
            vl0 = *(const bf16x8*)(Vl_ + gv + kc8);
            vl1 = *(const bf16x8*)(Vl_ + gv + kc8 + 64);
        }
        if (t < 15) {
            const size_t g = (size_t)((t + 1) * 128) * 64 + kc8;
            pkh0 = *(const bf16x8*)(Kh_ + g + (size_t)r0 * 64);
            pkh1 = *(const bf16x8*)(Kh_ + g + (size_t)(r0 + 64) * 64);
            pkl0 = *(const bf16x8*)(Kl_ + g + (size_t)r0 * 64);
            pkl1 = *(const bf16x8*)(Kl_ + g + (size_t)(r0 + 64) * 64);
        }
        f32x4 acc[4][2];
        qk_tile(acc);
        // p = 2^(s - m) * (1/l) ; write attn (stores drain asynchronously)
#pragma unroll
        for (int mf = 0; mf < 4; ++mf) {
            const int rg0 = bm + wm * 64 + mf * 16 + (lane >> 4) * 4;
#pragma unroll
            for (int nf = 0; nf < 2; ++nf) {
                const int col = t * 128 + wn * 32 + nf * 16 + (lane & 15);
#pragma unroll
                for (int r = 0; r < 4; ++r) {
                    const float p = E2(acc[mf][nf][r] - m_r[mf][r]) * l_r[mf][r];
                    acc[mf][nf][r] = p;
                    attn_b[(size_t)(rg0 + r) * S_LEN + col] = p;
                }
            }
        }
        bar();                                    // K reads done -> KV reusable for V
        *(bf16x8*)(KV + lv0) = vh0; *(bf16x8*)(KV + lv1) = vh1;
        *(bf16x8*)(KV + 16384 + lv0) = vl0; *(bf16x8*)(KV + 16384 + lv1) = vl1;
        // store P half-0 (cols 0..63, owned by waves wn<2)
        if (wn < 2) {
#pragma unroll
            for (int mf = 0; mf < 4; ++mf)
#pragma unroll
                for (int nf = 0; nf < 2; ++nf) {
                    const int k = (wn & 1) * 32 + nf * 16 + (lane & 15);
#pragma unroll
                    for (int r = 0; r < 4; ++r) {
                        const int rl = wm * 64 + mf * 16 + (lane >> 4) * 4 + r;
                        const int off = (((rl >> 4) * 2 + (k >> 5)) << 10) +
                                        (((k >> 3) & 3) << 8) + ((rl & 15) << 4) + ((k & 7) << 1);
                        __bf16 h, l;
                        split2(acc[mf][nf][r], h, l);
                        *(__bf16*)(PB + off) = h;
                        *(__bf16*)(PB + 16384 + off) = l;
                    }
                }
        }
        bar();                                    // V + P half-0 visible
#pragma unroll
        for (int kf = 0; kf < 2; ++kf) {
            const int offv = ((wn * 4 + 0 + kf) << 10) + lane * 16;
            const bf16x8 vhf = *(const bf16x8*)(KV + offv);
            const bf16x8 vlf = *(const bf16x8*)(KV + 16384 + offv);
#pragma unroll
            for (int mf = 0; mf < 4; ++mf) {
                const int offp = (((wm * 4 + mf) * 2 + kf) << 10) + lane * 16;
                const bf16x8 ph = *(const bf16x8*)(PB + offp);
                const bf16x8 pl = *(const bf16x8*)(PB + 16384 + offp);
                pv[mf] = mm16(pl, vhf, pv[mf]);
                pv[mf] = mm16(ph, vlf, pv[mf]);
                pv[mf] = mm16(ph, vhf, pv[mf]);
            }
        }
        bar();                                    // P half-0 reads done
        // store P half-1 (cols 64..127, owned by waves wn>=2)
        if (wn >= 2) {
#pragma unroll
            for (int mf = 0; mf < 4; ++mf)
#pragma unroll
                for (int nf = 0; nf < 2; ++nf) {
                    const int k = (wn & 1) * 32 + nf * 16 + (lane & 15);
#pragma unroll
                    for (int r = 0; r < 4; ++r) {
                        const int rl = wm * 64 + mf * 16 + (lane >> 4) * 4 + r;
                        const int off = (((rl >> 4) * 2 + (k >> 5)) << 10) +
                                        (((k >> 3) & 3) << 8) + ((rl & 15) << 4) + ((k & 7) << 1);
                        __bf16 h, l;
                        split2(acc[mf][nf][r], h, l);
                        *(__bf16*)(PB + off) = h;
                        *(__bf16*)(PB + 16384 + off) = l;
                    }
                }
        }
        bar();                                    // P half-1 visible
#pragma unroll
        for (int kf = 0; kf < 2; ++kf) {
            const int offv = ((wn * 4 + 2 + kf) << 10) + lane * 16;
            const bf16x8 vhf = *(const bf16x8*)(KV + offv);
            const bf16x8 vlf = *(const bf16x8*)(KV + 16384 + offv);
#pragma unroll
            for (int mf = 0; mf < 4; ++mf) {
                const int offp = (((wm * 4 + mf) * 2 + kf) << 10) + lane * 16;
                const bf16x8 ph = *(const bf16x8*)(PB + offp);
                const bf16x8 pl = *(const bf16x8*)(PB + 16384 + offp);
                pv[mf] = mm16(pl, vhf, pv[mf]);
                pv[mf] = mm16(ph, vlf, pv[mf]);
                pv[mf] = mm16(ph, vhf, pv[mf]);
            }
        }
    }

    // ctx epilogue: fp32 [b][s][1024] head slice (into the `out` region)
    const int b = bh >> 4, h = bh & 15;
#pragma unroll
    for (int mf = 0; mf < 4; ++mf)
#pragma unroll
        for (int r = 0; r < 4; ++r) {
            const int sg = bm + wm * 64 + mf * 16 + (lane >> 4) * 4 + r;
            const int d = wn * 16 + (lane & 15);
            ctx[((size_t)b * S_LEN + sg) * D_MODEL + h * 64 + d] = pv[mf][r];
        }
}

// ---------------------------------------------------------------------------
extern "C" void kernel_launch(void* const* d_in, const int* in_sizes, int n_in,
                              void* d_out, int out_size, void* d_ws, size_t ws_size,
                              hipStream_t stream)
{
    const float* q  = (const float*)d_in[0];
    const float* k  = (const float*)d_in[1];
    const float* v  = (const float*)d_in[2];
    const float* wq = (const float*)d_in[3];
    const float* bq = (const float*)d_in[4];
    const float* wk = (const float*)d_in[5];
    const float* bk = (const float*)d_in[6];
    const float* wv = (const float*)d_in[7];
    const float* bv = (const float*)d_in[8];
    const float* wo = (const float*)d_in[9];
    const float* bo = (const float*)d_in[10];

    float* out  = (float*)d_out;                          // [2,2048,1024]
    float* attn = out + (size_t)BATCH * S_LEN * D_MODEL;  // [2,16,2048,2048]

    // workspace (64 MB):
    //  0-16: weight splits (woT live through out_proj; wq/wk/wv dead after proj)
    // 16-32: Q hi/lo  -> reused as out_proj scratch after attn
    // 32-48: K hi/lo | 48-64: Vt hi/lo
    // ctx (fp32, 16 MB) lives in the `out` region of d_out during attn/out_proj.
    char* ws = (char*)d_ws;
    const size_t MB = 1024 * 1024;
    __bf16* WB   = (__bf16*)ws;
    __bf16* QHI  = (__bf16*)(ws + 16 * MB);
    __bf16* QLO  = (__bf16*)(ws + 24 * MB);
    __bf16* KHI  = (__bf16*)(ws + 32 * MB);
    __bf16* KLO  = (__bf16*)(ws + 40 * MB);
    __bf16* VTHI = (__bf16*)(ws + 48 * MB);
    __bf16* VTLO = (__bf16*)(ws + 56 * MB);
    float*  tmp  = (float*)(ws + 16 * MB);                // out_proj result

    const size_t W1M = 1048576;
    __bf16* WOT_HI = WB;
    __bf16* WOT_LO = WB + W1M;

    wsplit<<<dim3(16, 16, 4), dim3(256), 0, stream>>>(wq, wk, wv, wo, WB);

    // merged QKV projections (Q scaled by 0.125*log2e for exp2-domain softmax)
    qkv_proj<<<dim3(32, 8, 3), dim3(512), 0, stream>>>(
        q, k, v, WB, bq, bk, bv, QHI, QLO, KHI, KLO, VTHI, VTLO);

    // fused attention, both batches; ctx -> out region
    attn_fused<<<dim3(512), dim3(512), 0, stream>>>(
        QHI, QLO, KHI, KLO, VTHI, VTLO, attn, out);

    // output projection (M=4096 in one launch), then copy back into out
    out_proj<<<dim3(32, 8), dim3(512), 0, stream>>>(out, WOT_HI, WOT_LO, bo, tmp);
    hipMemcpyAsync(out, tmp, (size_t)BATCH * S_LEN * D_MODEL * sizeof(float),
                   hipMemcpyDeviceToDevice, stream);
}